// Round 2
// baseline (640.308 us; speedup 1.0000x reference)
//
#include <hip/hip_runtime.h>
#include <stdint.h>

typedef unsigned short u16;
typedef unsigned int u32;
typedef unsigned long long u64;

typedef __attribute__((ext_vector_type(8))) short bfrag;   // 8 bf16 (4 VGPRs)
typedef __attribute__((ext_vector_type(4))) float f32x4;   // 4 fp32 acc
typedef __attribute__((ext_vector_type(2))) float f32x2;   // packed fp32 pair (v_pk_*_f32)

// ---------- bf16 helpers (OCP bf16 = raw upper 16 bits of fp32) ----------
__device__ __forceinline__ float bf2f(u16 u) { return __uint_as_float(((u32)u) << 16); }
__device__ __forceinline__ u16 f2bf(float f) {
    u32 i = __float_as_uint(f);
    u32 r = i + 0x7fffu + ((i >> 16) & 1u);   // round-to-nearest-even
    return (u16)(r >> 16);
}
__device__ __forceinline__ float lo16(u32 u) { return __uint_as_float(u << 16); }
__device__ __forceinline__ float hi16(u32 u) { return __uint_as_float(u & 0xffff0000u); }
__device__ __forceinline__ u32 pack2(float a, float b) {
    return (u32)f2bf(a) | ((u32)f2bf(b) << 16);
}
#define RFL(x) __builtin_amdgcn_readfirstlane(x)

// 16-lane (row) sum via DPP row_ror rotate-adds: 4 dependent v_add_f32, no LDS pipe.
#define DPP_ROR_ADD(p, ctrl) \
    p += __int_as_float(__builtin_amdgcn_update_dpp(0, __float_as_int(p), ctrl, 0xF, 0xF, false))
__device__ __forceinline__ float red16(float p) {
    DPP_ROR_ADD(p, 0x128);   // ror 8
    DPP_ROR_ADD(p, 0x124);   // ror 4
    DPP_ROR_ADD(p, 0x122);   // ror 2
    DPP_ROR_ADD(p, 0x121);   // ror 1
    return p;                // every lane in the 16-row holds the row sum
}

// ---------- CSR build ----------
__global__ void deg_hist(const int* __restrict__ dst, int E, int* __restrict__ deg) {
    int e = blockIdx.x * blockDim.x + threadIdx.x;
    if (e < E) atomicAdd(&deg[dst[e]], 1);
}

#define SCAN_T 256
#define SCAN_E 8
#define SCAN_CHUNK 2048

__global__ void scan_partial(const int* __restrict__ deg, int n, int* __restrict__ partials) {
    __shared__ int sh[SCAN_T];
    int b = blockIdx.x, t = threadIdx.x;
    int base = b * SCAN_CHUNK + t * SCAN_E;
    int s = 0;
#pragma unroll
    for (int i = 0; i < SCAN_E; i++) { int idx = base + i; if (idx < n) s += deg[idx]; }
    sh[t] = s; __syncthreads();
    for (int off = SCAN_T / 2; off > 0; off >>= 1) {
        if (t < off) sh[t] += sh[t + off];
        __syncthreads();
    }
    if (t == 0) partials[b] = sh[0];
}

__global__ void scan_mid(int* __restrict__ partials, int nb) {
    if (threadIdx.x == 0 && blockIdx.x == 0) {
        int acc = 0;
        for (int i = 0; i < nb; i++) { int v = partials[i]; partials[i] = acc; acc += v; }
    }
}

__global__ void scan_final(const int* __restrict__ deg, int n, const int* __restrict__ partials,
                           int* __restrict__ offs, int E) {
    __shared__ int sh[SCAN_T];
    int b = blockIdx.x, t = threadIdx.x;
    int base = b * SCAN_CHUNK + t * SCAN_E;
    int loc[SCAN_E];
    int s = 0;
#pragma unroll
    for (int i = 0; i < SCAN_E; i++) {
        int idx = base + i;
        int v = (idx < n) ? deg[idx] : 0;
        loc[i] = s; s += v;
    }
    sh[t] = s; __syncthreads();
    for (int off = 1; off < SCAN_T; off <<= 1) {
        int v = 0;
        if (t >= off) v = sh[t - off];
        __syncthreads();
        if (t >= off) sh[t] += v;
        __syncthreads();
    }
    int tbase = partials[b] + sh[t] - s;   // exclusive base for this thread
#pragma unroll
    for (int i = 0; i < SCAN_E; i++) { int idx = base + i; if (idx < n) offs[idx] = tbase + loc[i]; }
    if (b == gridDim.x - 1 && t == SCAN_T - 1) offs[n] = E;
}

// ---------- fused CSR fill, split arrays: src[p] (4B) + attr[p] (64B raw fp32) ----------
__global__ void csr_fill_split(const int* __restrict__ srcv, const int* __restrict__ dstv,
                               const float4* __restrict__ ea, int E,
                               int* __restrict__ cursor,
                               int* __restrict__ csrc, float4* __restrict__ cattr) {
    int e = blockIdx.x * blockDim.x + threadIdx.x;
    if (e >= E) return;
    const float4* s = ea + (u64)e * 4;
    float4 v0 = s[0], v1 = s[1], v2 = s[2], v3 = s[3];
    int sr = srcv[e];
    int d = dstv[e];
    int p = atomicAdd(&cursor[d], 1);
    csrc[p] = sr;
    float4* dp = cattr + (u64)p * 4;
    dp[0] = v0; dp[1] = v1; dp[2] = v2; dp[3] = v3;
}

// ---------- W pre-pack: Wl,Wr (fp32, K x 64 each) -> bf16 B-fragment order ----------
template <int K>
__global__ void pack_w(const float* __restrict__ Wl, const float* __restrict__ Wr,
                       u32* __restrict__ Wb) {
    constexpr int NKS = K / 32;
    int t = blockIdx.x * blockDim.x + threadIdx.x;
    if (t >= 8 * NKS * 64) return;
    int lane = t & 63;
    int ks = (t >> 6) % NKS;
    int ct = (t >> 6) / NKS;
    int n = lane & 15, quad = lane >> 4;
    int c = ct * 16 + n;
    const float* W = (c < 64) ? Wl : Wr;
    int cc = c & 63;
    u32* d = Wb + (u64)t * 4;
#pragma unroll
    for (int p = 0; p < 4; p++) {
        int k0 = ks * 32 + quad * 8 + 2 * p;
        d[p] = pack2(W[(u64)k0 * 64 + cc], W[(u64)(k0 + 1) * 64 + cc]);
    }
}

// ---------- MFMA dual GEMM: [xl|xr] = X @ [Wl|Wr] + [bl|br] (bf16 out) ----------
template <int K, bool XF32>
__global__ __launch_bounds__(256) void gemm_mfma(const void* __restrict__ Xv,
                                                 const u32* __restrict__ Wb,
                                                 const float* __restrict__ bl,
                                                 const float* __restrict__ br,
                                                 int N, u16* __restrict__ xl, u16* __restrict__ xr) {
    constexpr int NKS = K / 32;
    int lane = threadIdx.x & 63;
    int gw = (blockIdx.x * 256 + threadIdx.x) >> 6;
    int row0 = gw * 16;
    if (row0 >= N) return;
    int m = lane & 15, quad = lane >> 4;

    f32x4 acc[8];
#pragma unroll
    for (int ct = 0; ct < 8; ct++) acc[ct] = (f32x4){0.f, 0.f, 0.f, 0.f};

#pragma unroll
    for (int ks = 0; ks < NKS; ks++) {
        bfrag a;
        if (XF32) {
            const float* xp = (const float*)Xv + (u64)(row0 + m) * K + ks * 32 + quad * 8;
            float4 v0 = *(const float4*)xp;
            float4 v1 = *(const float4*)(xp + 4);
            union { bfrag v; u32 d[4]; } au;
            au.d[0] = pack2(v0.x, v0.y); au.d[1] = pack2(v0.z, v0.w);
            au.d[2] = pack2(v1.x, v1.y); au.d[3] = pack2(v1.z, v1.w);
            a = au.v;
        } else {
            a = *(const bfrag*)((const u16*)Xv + (u64)(row0 + m) * K + ks * 32 + quad * 8);
        }
#pragma unroll
        for (int ct = 0; ct < 8; ct++) {
            bfrag b = *(const bfrag*)(Wb + (u64)((ct * NKS + ks) * 64 + lane) * 4);
            acc[ct] = __builtin_amdgcn_mfma_f32_16x16x32_bf16(a, b, acc[ct], 0, 0, 0);
        }
    }

    // Epilogue: C/D layout col=lane&15(=m), row=quad*4+reg
#pragma unroll
    for (int ct = 0; ct < 8; ct++) {
        float bv = (ct < 4) ? bl[ct * 16 + m] : br[(ct - 4) * 16 + m];
        u16* dbuf = (ct < 4) ? xl : xr;
        int cc = (ct & 3) * 16 + m;
#pragma unroll
        for (int r = 0; r < 4; r++) {
            int row = row0 + quad * 4 + r;
            dbuf[(u64)row * 64 + cc] = f2bf(acc[ct][r] + bv);
        }
    }
}

// ---------- GATv2 layer: wave/node, per-lane src preload + readlane, 4x unroll ----------
// Self-loop via linearity: mean(ea)@We == eesum/deg, accumulated in-register.
// Per-64-edge chunk, src indices are preloaded with ONE coalesced vector load and
// extracted per-edge via v_readlane -> the serial s_load(csrc)->gather chain is gone.
// 4-edge unroll issues all 4 xl[src] gathers before any compute (latency cover ~200cy
// per wave x ~8 waves/SIMD). ee transform runs as v_pk_fma_f32 on fp32 attrs (uniform
// s_loads); att pre-scaled by log2(e) so softmax weight is one raw v_exp_f32.
__global__ __launch_bounds__(256) void gat_layer(const u16* __restrict__ xl, const u16* __restrict__ xr,
                                                 const int* __restrict__ offs,
                                                 const int* __restrict__ csrc,   // src per CSR slot
                                                 const float* __restrict__ cattr,// 16 fp32 per slot
                                                 const float* __restrict__ We,   // 16 x 64, fp32
                                                 const float* __restrict__ att,  // 64 (= 4x16), fp32
                                                 const float* __restrict__ bias, // 64, fp32
                                                 int N, u16* __restrict__ out) {
    int l = threadIdx.x & 63;            // channel = h*16 + c
    int wid = RFL((int)((blockIdx.x * 256 + threadIdx.x) >> 6));
    int nw = gridDim.x * 4;
    f32x2 wec2[8];
#pragma unroll
    for (int k = 0; k < 8; k++) {
        wec2[k].x = We[(2 * k) * 64 + l];
        wec2[k].y = We[(2 * k + 1) * 64 + l];
    }
    float att_ls = att[l] * 1.44269504088896340736f;  // fold log2(e): w = exp2(alpha*log2e)
    float bias_l = bias[l];

    for (int n = wid; n < N; n += nw) {
        float xr_l = bf2f(xr[(u32)(n * 64 + l)]);
        float xl_self = bf2f(xl[(u32)(n * 64 + l)]);
        int a = RFL(offs[n]);
        int b = RFL(offs[n + 1]);

        float lsum0 = 0.f, lsum1 = 0.f, o0 = 0.f, o1 = 0.f, es0 = 0.f, es1 = 0.f;

        // compute-only edge body: xlv already gathered by caller
        auto edge_c = [&](const float* eap, float xlv, float& lsum, float& o, float& eesum) {
            f32x2 e0 = {0.f, 0.f}, e1 = {0.f, 0.f};   // dual packed accums: 4-deep chains
#pragma unroll
            for (int k = 0; k < 4; k++) {
                f32x2 a0 = *(const f32x2*)(eap + 4 * k);       // uniform -> s_load
                f32x2 a1 = *(const f32x2*)(eap + 4 * k + 2);
                e0 = __builtin_elementwise_fma(a0, wec2[2 * k], e0);      // v_pk_fma_f32
                e1 = __builtin_elementwise_fma(a1, wec2[2 * k + 1], e1);
            }
            f32x2 es = e0 + e1;                        // v_pk_add_f32
            float eef = es.x + es.y;
            eesum += eef;
            float z = (eef + xr_l) + xlv;
            z = fmaxf(z, 0.2f * z);                    // leaky_relu(0.2)
            float vv = red16(z * att_ls);              // DPP 16-lane sum
            float w;
            asm("v_exp_f32 %0, %1" : "=v"(w) : "v"(vv));   // exp2 of pre-scaled alpha
            lsum += w;
            o = fmaf(w, xlv, o);
        };

        for (int base = a; base < b; base += 64) {
            int rem = b - base;
            int cnt = rem < 64 ? rem : 64;
            int idx = base + l;
            int sv = csrc[idx < b ? idx : (b - 1)];    // coalesced per-lane preload
            int j = 0;
            for (; j + 4 <= cnt; j += 4) {
                int s0 = __builtin_amdgcn_readlane(sv, j);
                int s1 = __builtin_amdgcn_readlane(sv, j + 1);
                int s2 = __builtin_amdgcn_readlane(sv, j + 2);
                int s3 = __builtin_amdgcn_readlane(sv, j + 3);
                // issue all 4 gathers before any compute
                float xlv0 = bf2f(xl[(u32)(s0 * 64 + l)]);
                float xlv1 = bf2f(xl[(u32)(s1 * 64 + l)]);
                float xlv2 = bf2f(xl[(u32)(s2 * 64 + l)]);
                float xlv3 = bf2f(xl[(u32)(s3 * 64 + l)]);
                const float* ep = cattr + (u64)(base + j) * 16;
                edge_c(ep,      xlv0, lsum0, o0, es0);
                edge_c(ep + 16, xlv1, lsum1, o1, es1);
                edge_c(ep + 32, xlv2, lsum0, o0, es0);
                edge_c(ep + 48, xlv3, lsum1, o1, es1);
            }
            for (; j < cnt; j++) {
                int s0 = __builtin_amdgcn_readlane(sv, j);
                float xlv0 = bf2f(xl[(u32)(s0 * 64 + l)]);
                edge_c(cattr + (u64)(base + j) * 16, xlv0, lsum0, o0, es0);
            }
        }

        float lsum = lsum0 + lsum1;
        float o = o0 + o1;
        float eesum = es0 + es1;

        { // self-loop: ee = eesum/deg (mean edge-attr transform), src = n
            int deg = b - a;
            float inv = (deg > 0) ? 1.f / (float)deg : 0.f;
            float z = (eesum * inv + xr_l) + xl_self;
            z = fmaxf(z, 0.2f * z);
            float vv = red16(z * att_ls);
            float w;
            asm("v_exp_f32 %0, %1" : "=v"(w) : "v"(vv));
            lsum += w;
            o = fmaf(w, xl_self, o);
        }

        float res = o / (lsum + 1e-16f) + bias_l;
        res = fmaxf(res, 0.f);                        // relu after each GAT layer
        out[(u32)(n * 64 + l)] = f2bf(res);
    }
}

// ---------- MLP head: relu(h @ W1 + b1) @ W2 + b2 -> sigmoid (fp32 out) ----------
__global__ __launch_bounds__(256) void mlp_head(const u16* __restrict__ h,
                                                const float* __restrict__ W1, const float* __restrict__ b1,
                                                const float* __restrict__ W2, const float* __restrict__ b2,
                                                int N, float* __restrict__ out) {
    __shared__ float w1[64 * 16];
    __shared__ float sb1[16];
    __shared__ float w2[16];
    for (int i = threadIdx.x; i < 64 * 16; i += 256) w1[i] = W1[i];
    if (threadIdx.x < 16) { sb1[threadIdx.x] = b1[threadIdx.x]; w2[threadIdx.x] = W2[threadIdx.x]; }
    __syncthreads();
    float b2v = b2[0];
    int n = blockIdx.x * blockDim.x + threadIdx.x;
    if (n < N) {
        float hv[64];
        const u32* hp = (const u32*)(h + (u64)n * 64);
#pragma unroll
        for (int i = 0; i < 32; i++) { u32 u = hp[i]; hv[2 * i] = lo16(u); hv[2 * i + 1] = hi16(u); }
        float z = b2v;
        for (int j = 0; j < 16; j++) {
            float acc = sb1[j];
#pragma unroll
            for (int k = 0; k < 64; k++) acc = fmaf(hv[k], w1[k * 16 + j], acc);
            acc = fmaxf(acc, 0.f);
            z = fmaf(acc, w2[j], z);
        }
        out[n] = 1.f / (1.f + __expf(-z));
    }
}

// ---------- launch ----------
extern "C" void kernel_launch(void* const* d_in, const int* in_sizes, int n_in,
                              void* d_out, int out_size, void* d_ws, size_t ws_size,
                              hipStream_t stream) {
    const float* x    = (const float*)d_in[0];
    const int*   ei   = (const int*)d_in[1];
    const float* ea   = (const float*)d_in[2];
    const float* Wl1  = (const float*)d_in[3];
    const float* bl1  = (const float*)d_in[4];
    const float* Wr1  = (const float*)d_in[5];
    const float* br1  = (const float*)d_in[6];
    const float* We1  = (const float*)d_in[7];
    const float* att1 = (const float*)d_in[8];
    const float* bias1= (const float*)d_in[9];
    const float* Wl2  = (const float*)d_in[10];
    const float* bl2  = (const float*)d_in[11];
    const float* Wr2  = (const float*)d_in[12];
    const float* br2  = (const float*)d_in[13];
    const float* We2  = (const float*)d_in[14];
    const float* att2 = (const float*)d_in[15];
    const float* bias2= (const float*)d_in[16];
    const float* W1   = (const float*)d_in[17];
    const float* b1   = (const float*)d_in[18];
    const float* W2   = (const float*)d_in[19];
    const float* b2   = (const float*)d_in[20];
    float* out = (float*)d_out;

    const int N = in_sizes[0] / 128;
    const int E = in_sizes[1] / 2;
    const int* srcv = ei;
    const int* dstv = ei + E;

    uint8_t* p = (uint8_t*)d_ws;
    auto carve = [&](size_t bytes) -> void* {
        void* r = (void*)p;
        p += (bytes + 255) & ~(size_t)255;
        return r;
    };
    int*  deg     = (int*)carve((size_t)N * 4);
    int*  cursor  = (int*)carve((size_t)N * 4);
    int*  offs    = (int*)carve((size_t)(N + 1) * 4);
    int*  partials= (int*)carve(4096);
    int*  csrc    = (int*)carve((size_t)E * 4);
    float* cattr  = (float*)carve((size_t)E * 64);   // 16 fp32 per edge
    u16*  xl      = (u16*)carve((size_t)N * 64 * 2);
    u16*  xr      = (u16*)carve((size_t)N * 64 * 2);
    u16*  hb      = (u16*)carve((size_t)N * 64 * 2);
    u32*  wb1     = (u32*)carve(8 * 4 * 64 * 16);   // K=128 packed W
    u32*  wb2     = (u32*)carve(8 * 2 * 64 * 16);   // K=64 packed W
    (void)ws_size; (void)n_in; (void)out_size;

    hipMemsetAsync(deg, 0, (size_t)N * 4, stream);

    const int B = 256;
    pack_w<128><<<8, 256, 0, stream>>>(Wl1, Wr1, wb1);
    pack_w<64><<<4, 256, 0, stream>>>(Wl2, Wr2, wb2);

    deg_hist<<<(E + B - 1) / B, B, 0, stream>>>(dstv, E, deg);
    int nb = (N + SCAN_CHUNK - 1) / SCAN_CHUNK;
    scan_partial<<<nb, SCAN_T, 0, stream>>>(deg, N, partials);
    scan_mid<<<1, 64, 0, stream>>>(partials, nb);
    scan_final<<<nb, SCAN_T, 0, stream>>>(deg, N, partials, offs, E);
    hipMemcpyAsync(cursor, offs, (size_t)N * 4, hipMemcpyDeviceToDevice, stream);
    csr_fill_split<<<(E + B - 1) / B, B, 0, stream>>>(srcv, dstv, (const float4*)ea, E,
                                                      cursor, csrc, (float4*)cattr);

    int gemm_blocks = (N / 16 + 3) / 4;
    // Layer 1
    gemm_mfma<128, true><<<gemm_blocks, 256, 0, stream>>>(x, wb1, bl1, br1, N, xl, xr);
    gat_layer<<<8192, 256, 0, stream>>>(xl, xr, offs, csrc, cattr,
                                        We1, att1, bias1, N, hb);
    // Layer 2
    gemm_mfma<64, false><<<gemm_blocks, 256, 0, stream>>>(hb, wb2, bl2, br2, N, xl, xr);
    gat_layer<<<8192, 256, 0, stream>>>(xl, xr, offs, csrc, cattr,
                                        We2, att2, bias2, N, hb);
    // Head
    mlp_head<<<(N + B - 1) / B, B, 0, stream>>>(hb, W1, b1, W2, b2, N, out);
}

// Round 4
// 624.636 us; speedup vs baseline: 1.0251x; 1.0251x over previous
//
#include <hip/hip_runtime.h>
#include <stdint.h>

typedef unsigned short u16;
typedef unsigned int u32;
typedef unsigned long long u64;

typedef __attribute__((ext_vector_type(8))) short bfrag;   // 8 bf16 (4 VGPRs)
typedef __attribute__((ext_vector_type(4))) float f32x4;   // 4 fp32 acc
typedef __attribute__((ext_vector_type(2))) float f32x2;   // packed fp32 pair (v_pk_*_f32)

// ---------- bf16 helpers (OCP bf16 = raw upper 16 bits of fp32) ----------
__device__ __forceinline__ float bf2f(u16 u) { return __uint_as_float(((u32)u) << 16); }
__device__ __forceinline__ u16 f2bf(float f) {
    u32 i = __float_as_uint(f);
    u32 r = i + 0x7fffu + ((i >> 16) & 1u);   // round-to-nearest-even
    return (u16)(r >> 16);
}
__device__ __forceinline__ float lo16(u32 u) { return __uint_as_float(u << 16); }
__device__ __forceinline__ float hi16(u32 u) { return __uint_as_float(u & 0xffff0000u); }
__device__ __forceinline__ u32 pack2(float a, float b) {
    return (u32)f2bf(a) | ((u32)f2bf(b) << 16);
}
#define RFL(x) __builtin_amdgcn_readfirstlane(x)

// 16-lane (row) sum via DPP row_ror rotate-adds.
#define DPP_ROR_ADD(p, ctrl) \
    p += __int_as_float(__builtin_amdgcn_update_dpp(0, __float_as_int(p), ctrl, 0xF, 0xF, false))
__device__ __forceinline__ float red16(float p) {
    DPP_ROR_ADD(p, 0x128);   // ror 8
    DPP_ROR_ADD(p, 0x124);   // ror 4
    DPP_ROR_ADD(p, 0x122);   // ror 2
    DPP_ROR_ADD(p, 0x121);   // ror 1
    return p;                // every lane in the 16-row holds the row sum
}

// ---------- CSR build ----------
// rank_hist: one atomic per edge does double duty: counts degree AND yields the
// edge's slot-rank within its dst bucket. csr_fill then needs NO atomics.
__global__ void rank_hist(const int* __restrict__ dst, int E,
                          int* __restrict__ deg, int* __restrict__ rank) {
    int e = blockIdx.x * blockDim.x + threadIdx.x;
    if (e < E) rank[e] = atomicAdd(&deg[dst[e]], 1);
}

#define SCAN_T 256
#define SCAN_E 8
#define SCAN_CHUNK 2048

__global__ void scan_partial(const int* __restrict__ deg, int n, int* __restrict__ partials) {
    __shared__ int sh[SCAN_T];
    int b = blockIdx.x, t = threadIdx.x;
    int base = b * SCAN_CHUNK + t * SCAN_E;
    int s = 0;
#pragma unroll
    for (int i = 0; i < SCAN_E; i++) { int idx = base + i; if (idx < n) s += deg[idx]; }
    sh[t] = s; __syncthreads();
    for (int off = SCAN_T / 2; off > 0; off >>= 1) {
        if (t < off) sh[t] += sh[t + off];
        __syncthreads();
    }
    if (t == 0) partials[b] = sh[0];
}

__global__ void scan_mid(int* __restrict__ partials, int nb) {
    if (threadIdx.x == 0 && blockIdx.x == 0) {
        int acc = 0;
        for (int i = 0; i < nb; i++) { int v = partials[i]; partials[i] = acc; acc += v; }
    }
}

__global__ void scan_final(const int* __restrict__ deg, int n, const int* __restrict__ partials,
                           int* __restrict__ offs, int E) {
    __shared__ int sh[SCAN_T];
    int b = blockIdx.x, t = threadIdx.x;
    int base = b * SCAN_CHUNK + t * SCAN_E;
    int loc[SCAN_E];
    int s = 0;
#pragma unroll
    for (int i = 0; i < SCAN_E; i++) {
        int idx = base + i;
        int v = (idx < n) ? deg[idx] : 0;
        loc[i] = s; s += v;
    }
    sh[t] = s; __syncthreads();
    for (int off = 1; off < SCAN_T; off <<= 1) {
        int v = 0;
        if (t >= off) v = sh[t - off];
        __syncthreads();
        if (t >= off) sh[t] += v;
        __syncthreads();
    }
    int tbase = partials[b] + sh[t] - s;   // exclusive base for this thread
#pragma unroll
    for (int i = 0; i < SCAN_E; i++) { int idx = base + i; if (idx < n) offs[idx] = tbase + loc[i]; }
    if (b == gridDim.x - 1 && t == SCAN_T - 1) offs[n] = E;
}

// ---------- CSR fill, index-only: cse[p] = {src, edge_id}. NO attr copy. ----------
// Attrs are read directly from ea in gat_layer via uniform s_loads, so permuting
// the 64B attr rows (102MB scatter-write + 2x re-read) is pure waste.
__global__ void csr_fill_idx(const int* __restrict__ srcv, const int* __restrict__ dstv,
                             const int* __restrict__ rank,
                             const int* __restrict__ offs, int E,
                             int2* __restrict__ cse) {
    int e = blockIdx.x * blockDim.x + threadIdx.x;
    if (e >= E) return;
    int d = dstv[e];
    int p = offs[d] + rank[e];
    cse[p] = make_int2(srcv[e], e);
}

// ---------- W pre-pack: Wl,Wr (fp32, K x 64 each) -> bf16 B-fragment order ----------
template <int K>
__global__ void pack_w(const float* __restrict__ Wl, const float* __restrict__ Wr,
                       u32* __restrict__ Wb) {
    constexpr int NKS = K / 32;
    int t = blockIdx.x * blockDim.x + threadIdx.x;
    if (t >= 8 * NKS * 64) return;
    int lane = t & 63;
    int ks = (t >> 6) % NKS;
    int ct = (t >> 6) / NKS;
    int n = lane & 15, quad = lane >> 4;
    int c = ct * 16 + n;
    const float* W = (c < 64) ? Wl : Wr;
    int cc = c & 63;
    u32* d = Wb + (u64)t * 4;
#pragma unroll
    for (int p = 0; p < 4; p++) {
        int k0 = ks * 32 + quad * 8 + 2 * p;
        d[p] = pack2(W[(u64)k0 * 64 + cc], W[(u64)(k0 + 1) * 64 + cc]);
    }
}

// ---------- MFMA dual GEMM: [xl|xr] = X @ [Wl|Wr] + [bl|br] (bf16 out) ----------
template <int K, bool XF32>
__global__ __launch_bounds__(256) void gemm_mfma(const void* __restrict__ Xv,
                                                 const u32* __restrict__ Wb,
                                                 const float* __restrict__ bl,
                                                 const float* __restrict__ br,
                                                 int N, u16* __restrict__ xl, u16* __restrict__ xr) {
    constexpr int NKS = K / 32;
    int lane = threadIdx.x & 63;
    int gw = (blockIdx.x * 256 + threadIdx.x) >> 6;
    int row0 = gw * 16;
    if (row0 >= N) return;
    int m = lane & 15, quad = lane >> 4;

    f32x4 acc[8];
#pragma unroll
    for (int ct = 0; ct < 8; ct++) acc[ct] = (f32x4){0.f, 0.f, 0.f, 0.f};

#pragma unroll
    for (int ks = 0; ks < NKS; ks++) {
        bfrag a;
        if (XF32) {
            const float* xp = (const float*)Xv + (u64)(row0 + m) * K + ks * 32 + quad * 8;
            float4 v0 = *(const float4*)xp;
            float4 v1 = *(const float4*)(xp + 4);
            union { bfrag v; u32 d[4]; } au;
            au.d[0] = pack2(v0.x, v0.y); au.d[1] = pack2(v0.z, v0.w);
            au.d[2] = pack2(v1.x, v1.y); au.d[3] = pack2(v1.z, v1.w);
            a = au.v;
        } else {
            a = *(const bfrag*)((const u16*)Xv + (u64)(row0 + m) * K + ks * 32 + quad * 8);
        }
#pragma unroll
        for (int ct = 0; ct < 8; ct++) {
            bfrag b = *(const bfrag*)(Wb + (u64)((ct * NKS + ks) * 64 + lane) * 4);
            acc[ct] = __builtin_amdgcn_mfma_f32_16x16x32_bf16(a, b, acc[ct], 0, 0, 0);
        }
    }

    // Epilogue: C/D layout col=lane&15(=m), row=quad*4+reg
#pragma unroll
    for (int ct = 0; ct < 8; ct++) {
        float bv = (ct < 4) ? bl[ct * 16 + m] : br[(ct - 4) * 16 + m];
        u16* dbuf = (ct < 4) ? xl : xr;
        int cc = (ct & 3) * 16 + m;
#pragma unroll
        for (int r = 0; r < 4; r++) {
            int row = row0 + quad * 4 + r;
            dbuf[(u64)row * 64 + cc] = f2bf(acc[ct][r] + bv);
        }
    }
}

// ---------- GATv2 layer: wave/node, staged 4-edge pipeline, direct-ea attrs ----------
// Per 64-edge chunk: ONE coalesced int2 preload of {src,eid}; per 4-edge group:
// [readlane idx -> 4 gathers + 4 uniform s_load attr rows] -> [4 dots, k-outer:
// 8 indep pk_fma chains] -> [z/leaky/scale] -> [4 interleaved red16 (DPP hazards
// hidden)] -> [4 exps] -> [accumulate]. Self-loop via linearity:
// mean(ea)@We == eesum/deg. att pre-scaled by log2(e): weight = one v_exp_f32.
__global__ __launch_bounds__(256) void gat_layer(const u16* __restrict__ xl, const u16* __restrict__ xr,
                                                 const int* __restrict__ offs,
                                                 const int2* __restrict__ cse,   // {src, eid} per CSR slot
                                                 const float* __restrict__ ea,   // E x 16 fp32 (original order)
                                                 const float* __restrict__ We,   // 16 x 64, fp32
                                                 const float* __restrict__ att,  // 64 (= 4x16), fp32
                                                 const float* __restrict__ bias, // 64, fp32
                                                 int N, u16* __restrict__ out) {
    int l = threadIdx.x & 63;            // channel = h*16 + c
    int wid = RFL((int)((blockIdx.x * 256 + threadIdx.x) >> 6));
    int nw = gridDim.x * 4;
    f32x2 wec2[8];
#pragma unroll
    for (int k = 0; k < 8; k++) {
        wec2[k].x = We[(2 * k) * 64 + l];
        wec2[k].y = We[(2 * k + 1) * 64 + l];
    }
    float att_ls = att[l] * 1.44269504088896340736f;  // fold log2(e): w = exp2(alpha*log2e)
    float bias_l = bias[l];

    for (int n = wid; n < N; n += nw) {
        float xr_l = bf2f(xr[(u32)(n * 64 + l)]);
        float xl_self = bf2f(xl[(u32)(n * 64 + l)]);
        int a = RFL(offs[n]);
        int b = RFL(offs[n + 1]);

        float lsum0 = 0.f, lsum1 = 0.f, o0 = 0.f, o1 = 0.f, es0 = 0.f, es1 = 0.f;

        // single-edge (tail) body
        auto edge_1 = [&](const float* eap, float xlv, float& lsum, float& o, float& eesum) {
            f32x2 e0 = {0.f, 0.f}, e1 = {0.f, 0.f};
#pragma unroll
            for (int k = 0; k < 4; k++) {
                f32x2 a0 = *(const f32x2*)(eap + 4 * k);
                f32x2 a1 = *(const f32x2*)(eap + 4 * k + 2);
                e0 = __builtin_elementwise_fma(a0, wec2[2 * k], e0);
                e1 = __builtin_elementwise_fma(a1, wec2[2 * k + 1], e1);
            }
            f32x2 es = e0 + e1;
            float eef = es.x + es.y;
            eesum += eef;
            float z = (eef + xr_l) + xlv;
            z = fmaxf(z, 0.2f * z);
            float vv = red16(z * att_ls);
            float w;
            asm("v_exp_f32 %0, %1" : "=v"(w) : "v"(vv));
            lsum += w;
            o = fmaf(w, xlv, o);
        };

        for (int base = a; base < b; base += 64) {
            int rem = b - base;
            int cnt = rem < 64 ? rem : 64;
            int idx = base + l;
            int2 sev = cse[idx < b ? idx : (b - 1)];   // coalesced per-lane preload
            int sv = sev.x, ev = sev.y;
            int j = 0;
            for (; j + 4 <= cnt; j += 4) {
                // --- phase 1: indices (uniform), gathers + uniform attr rows
                int s0 = __builtin_amdgcn_readlane(sv, j);
                int s1 = __builtin_amdgcn_readlane(sv, j + 1);
                int s2 = __builtin_amdgcn_readlane(sv, j + 2);
                int s3 = __builtin_amdgcn_readlane(sv, j + 3);
                int e0i = __builtin_amdgcn_readlane(ev, j);
                int e1i = __builtin_amdgcn_readlane(ev, j + 1);
                int e2i = __builtin_amdgcn_readlane(ev, j + 2);
                int e3i = __builtin_amdgcn_readlane(ev, j + 3);
                float xlv0 = bf2f(xl[(u32)(s0 * 64 + l)]);
                float xlv1 = bf2f(xl[(u32)(s1 * 64 + l)]);
                float xlv2 = bf2f(xl[(u32)(s2 * 64 + l)]);
                float xlv3 = bf2f(xl[(u32)(s3 * 64 + l)]);
                const float* ep[4] = { ea + (u64)e0i * 16, ea + (u64)e1i * 16,
                                       ea + (u64)e2i * 16, ea + (u64)e3i * 16 };
                // --- phase 2: 4 dots, k-outer / edge-inner -> 8 independent chains
                f32x2 p0[4], p1[4];
#pragma unroll
                for (int u = 0; u < 4; u++) { p0[u] = (f32x2){0.f, 0.f}; p1[u] = (f32x2){0.f, 0.f}; }
#pragma unroll
                for (int k = 0; k < 4; k++) {
#pragma unroll
                    for (int u = 0; u < 4; u++) {
                        f32x2 a0 = *(const f32x2*)(ep[u] + 4 * k);       // uniform -> s_load
                        f32x2 a1 = *(const f32x2*)(ep[u] + 4 * k + 2);
                        p0[u] = __builtin_elementwise_fma(a0, wec2[2 * k], p0[u]);
                        p1[u] = __builtin_elementwise_fma(a1, wec2[2 * k + 1], p1[u]);
                    }
                }
                // --- phase 3: finish dots, z, leaky, att-scale
                float xlv[4] = {xlv0, xlv1, xlv2, xlv3};
                float zz[4], eef[4];
#pragma unroll
                for (int u = 0; u < 4; u++) {
                    f32x2 es = p0[u] + p1[u];
                    eef[u] = es.x + es.y;
                    float z = (eef[u] + xr_l) + xlv[u];
                    z = fmaxf(z, 0.2f * z);
                    zz[u] = z * att_ls;
                }
                es0 += eef[0] + eef[2];
                es1 += eef[1] + eef[3];
                // --- phase 4: 4 interleaved red16 (hides DPP hazards)
#define R4(ctrl) { DPP_ROR_ADD(zz[0], ctrl); DPP_ROR_ADD(zz[1], ctrl); \
                   DPP_ROR_ADD(zz[2], ctrl); DPP_ROR_ADD(zz[3], ctrl); }
                R4(0x128) R4(0x124) R4(0x122) R4(0x121)
#undef R4
                // --- phase 5: 4 exps back-to-back, then accumulate
                float w0, w1, w2, w3;
                asm("v_exp_f32 %0, %1" : "=v"(w0) : "v"(zz[0]));
                asm("v_exp_f32 %0, %1" : "=v"(w1) : "v"(zz[1]));
                asm("v_exp_f32 %0, %1" : "=v"(w2) : "v"(zz[2]));
                asm("v_exp_f32 %0, %1" : "=v"(w3) : "v"(zz[3]));
                lsum0 += w0 + w2;
                lsum1 += w1 + w3;
                o0 = fmaf(w0, xlv0, o0);
                o1 = fmaf(w1, xlv1, o1);
                o0 = fmaf(w2, xlv2, o0);
                o1 = fmaf(w3, xlv3, o1);
            }
            for (; j < cnt; j++) {
                int s0 = __builtin_amdgcn_readlane(sv, j);
                int e0i = __builtin_amdgcn_readlane(ev, j);
                float xlv0 = bf2f(xl[(u32)(s0 * 64 + l)]);
                edge_1(ea + (u64)e0i * 16, xlv0, lsum0, o0, es0);
            }
        }

        float lsum = lsum0 + lsum1;
        float o = o0 + o1;
        float eesum = es0 + es1;

        { // self-loop: ee = eesum/deg (mean edge-attr transform), src = n
            int deg = b - a;
            float inv = (deg > 0) ? 1.f / (float)deg : 0.f;
            float z = (eesum * inv + xr_l) + xl_self;
            z = fmaxf(z, 0.2f * z);
            float vv = red16(z * att_ls);
            float w;
            asm("v_exp_f32 %0, %1" : "=v"(w) : "v"(vv));
            lsum += w;
            o = fmaf(w, xl_self, o);
        }

        float res = o / (lsum + 1e-16f) + bias_l;
        res = fmaxf(res, 0.f);                        // relu after each GAT layer
        out[(u32)(n * 64 + l)] = f2bf(res);
    }
}

// ---------- MLP head: relu(h @ W1 + b1) @ W2 + b2 -> sigmoid (fp32 out) ----------
__global__ __launch_bounds__(256) void mlp_head(const u16* __restrict__ h,
                                                const float* __restrict__ W1, const float* __restrict__ b1,
                                                const float* __restrict__ W2, const float* __restrict__ b2,
                                                int N, float* __restrict__ out) {
    __shared__ float w1[64 * 16];
    __shared__ float sb1[16];
    __shared__ float w2[16];
    for (int i = threadIdx.x; i < 64 * 16; i += 256) w1[i] = W1[i];
    if (threadIdx.x < 16) { sb1[threadIdx.x] = b1[threadIdx.x]; w2[threadIdx.x] = W2[threadIdx.x]; }
    __syncthreads();
    float b2v = b2[0];
    int n = blockIdx.x * blockDim.x + threadIdx.x;
    if (n < N) {
        float hv[64];
        const u32* hp = (const u32*)(h + (u64)n * 64);
#pragma unroll
        for (int i = 0; i < 32; i++) { u32 u = hp[i]; hv[2 * i] = lo16(u); hv[2 * i + 1] = hi16(u); }
        float z = b2v;
        for (int j = 0; j < 16; j++) {
            float acc = sb1[j];
#pragma unroll
            for (int k = 0; k < 64; k++) acc = fmaf(hv[k], w1[k * 16 + j], acc);
            acc = fmaxf(acc, 0.f);
            z = fmaf(acc, w2[j], z);
        }
        out[n] = 1.f / (1.f + __expf(-z));
    }
}

// ---------- launch ----------
extern "C" void kernel_launch(void* const* d_in, const int* in_sizes, int n_in,
                              void* d_out, int out_size, void* d_ws, size_t ws_size,
                              hipStream_t stream) {
    const float* x    = (const float*)d_in[0];
    const int*   ei   = (const int*)d_in[1];
    const float* ea   = (const float*)d_in[2];
    const float* Wl1  = (const float*)d_in[3];
    const float* bl1  = (const float*)d_in[4];
    const float* Wr1  = (const float*)d_in[5];
    const float* br1  = (const float*)d_in[6];
    const float* We1  = (const float*)d_in[7];
    const float* att1 = (const float*)d_in[8];
    const float* bias1= (const float*)d_in[9];
    const float* Wl2  = (const float*)d_in[10];
    const float* bl2  = (const float*)d_in[11];
    const float* Wr2  = (const float*)d_in[12];
    const float* br2  = (const float*)d_in[13];
    const float* We2  = (const float*)d_in[14];
    const float* att2 = (const float*)d_in[15];
    const float* bias2= (const float*)d_in[16];
    const float* W1   = (const float*)d_in[17];
    const float* b1   = (const float*)d_in[18];
    const float* W2   = (const float*)d_in[19];
    const float* b2   = (const float*)d_in[20];
    float* out = (float*)d_out;

    const int N = in_sizes[0] / 128;
    const int E = in_sizes[1] / 2;
    const int* srcv = ei;
    const int* dstv = ei + E;

    uint8_t* p = (uint8_t*)d_ws;
    auto carve = [&](size_t bytes) -> void* {
        void* r = (void*)p;
        p += (bytes + 255) & ~(size_t)255;
        return r;
    };
    int*  deg     = (int*)carve((size_t)N * 4);
    int*  rank    = (int*)carve((size_t)E * 4);
    int*  offs    = (int*)carve((size_t)(N + 1) * 4);
    int*  partials= (int*)carve(4096);
    int2* cse     = (int2*)carve((size_t)E * 8);    // {src, eid} per CSR slot
    u16*  xl      = (u16*)carve((size_t)N * 64 * 2);
    u16*  xr      = (u16*)carve((size_t)N * 64 * 2);
    u16*  hb      = (u16*)carve((size_t)N * 64 * 2);
    u32*  wb1     = (u32*)carve(8 * 4 * 64 * 16);   // K=128 packed W
    u32*  wb2     = (u32*)carve(8 * 2 * 64 * 16);   // K=64 packed W
    (void)ws_size; (void)n_in; (void)out_size;

    hipMemsetAsync(deg, 0, (size_t)N * 4, stream);

    const int B = 256;
    pack_w<128><<<8, 256, 0, stream>>>(Wl1, Wr1, wb1);
    pack_w<64><<<4, 256, 0, stream>>>(Wl2, Wr2, wb2);

    rank_hist<<<(E + B - 1) / B, B, 0, stream>>>(dstv, E, deg, rank);
    int nb = (N + SCAN_CHUNK - 1) / SCAN_CHUNK;
    scan_partial<<<nb, SCAN_T, 0, stream>>>(deg, N, partials);
    scan_mid<<<1, 64, 0, stream>>>(partials, nb);
    scan_final<<<nb, SCAN_T, 0, stream>>>(deg, N, partials, offs, E);
    csr_fill_idx<<<(E + B - 1) / B, B, 0, stream>>>(srcv, dstv, rank, offs, E, cse);

    int gemm_blocks = (N / 16 + 3) / 4;
    // Layer 1
    gemm_mfma<128, true><<<gemm_blocks, 256, 0, stream>>>(x, wb1, bl1, br1, N, xl, xr);
    gat_layer<<<8192, 256, 0, stream>>>(xl, xr, offs, cse, ea,
                                        We1, att1, bias1, N, hb);
    // Layer 2
    gemm_mfma<64, false><<<gemm_blocks, 256, 0, stream>>>(hb, wb2, bl2, br2, N, xl, xr);
    gat_layer<<<8192, 256, 0, stream>>>(xl, xr, offs, cse, ea,
                                        We2, att2, bias2, N, hb);
    // Head
    mlp_head<<<(N + B - 1) / B, B, 0, stream>>>(hb, W1, b1, W2, b2, N, out);
}